// Round 5
// baseline (118.633 us; speedup 1.0000x reference)
//
#include <hip/hip_runtime.h>
#include <hip/hip_bf16.h>
#include <math.h>

// RelativeGeoSymLoss: B=8, N=4096 symmetric chamfer + trans L1.
// R5: R4 wave-owns-rows structure, register-pressure fixed.
//   - RW=8 rows/wave (live set ~50 VGPR, fits the 64-reg cap)
//   - __launch_bounds__(256,8): 8 waves/SIMD, grid 2048 = 8 blocks/CU
//   - no aw[] array (A.w re-loaded in epilogue), mm-unroll 2
// ws layout: pts [2][B][N] float4 (x,y,z,||.||^2) only.

#define TPB 256
#define RW  8    // rows per wave

__device__ __forceinline__ void rel_tf(const float* __restrict__ Ra,
                                       const float* __restrict__ ta,
                                       const float* __restrict__ Rb,
                                       const float* __restrict__ tb,
                                       float* R, float* t) {
#pragma unroll
    for (int i = 0; i < 3; i++)
#pragma unroll
        for (int k = 0; k < 3; k++)
            R[i * 3 + k] = Ra[i * 3 + 0] * Rb[k * 3 + 0]
                         + Ra[i * 3 + 1] * Rb[k * 3 + 1]
                         + Ra[i * 3 + 2] * Rb[k * 3 + 2];
#pragma unroll
    for (int i = 0; i < 3; i++)
        t[i] = ta[i] - (R[i * 3 + 0] * tb[0] + R[i * 3 + 1] * tb[1]
                      + R[i * 3 + 2] * tb[2]);
}

// Fused: relative transforms + point transform + out init.
__global__ void k_prep(const float* __restrict__ pred_rot,
                       const float* __restrict__ pred_trans,
                       const float* __restrict__ ctx_hyp_rot,
                       const float* __restrict__ ctx_hyp_trans,
                       const float* __restrict__ gt_rot,
                       const float* __restrict__ gt_trans,
                       const float* __restrict__ ctx_gt_rot,
                       const float* __restrict__ ctx_gt_trans,
                       const float* __restrict__ mp,
                       float4* __restrict__ pts,
                       float* __restrict__ out, int B, int N) {
    int idx = blockIdx.x * blockDim.x + threadIdx.x;
    if (idx >= B * N) return;
    int b = idx / N;
    float px = mp[idx * 3 + 0], py = mp[idx * 3 + 1], pz = mp[idx * 3 + 2];
    float R[9], t[3];
#pragma unroll
    for (int g = 0; g < 2; g++) {
        if (g == 0)
            rel_tf(pred_rot + b * 9, pred_trans + b * 3,
                   ctx_hyp_rot + b * 9, ctx_hyp_trans + b * 3, R, t);
        else
            rel_tf(gt_rot + b * 9, gt_trans + b * 3,
                   ctx_gt_rot + b * 9, ctx_gt_trans + b * 3, R, t);
        float x = R[0] * px + R[1] * py + R[2] * pz + t[0];
        float y = R[3] * px + R[4] * py + R[5] * pz + t[1];
        float z = R[6] * px + R[7] * py + R[8] * pz + t[2];
        pts[(size_t)g * B * N + idx] = make_float4(x, y, z, x * x + y * y + z * z);
    }
    if (idx == 0) {
        out[0] = 0.0f;
        float lt = 0.0f;
        for (int bb = 0; bb < B; bb++) {
            float Rp[9], tp[3], Rg[9], tg[3];
            rel_tf(pred_rot + bb * 9, pred_trans + bb * 3,
                   ctx_hyp_rot + bb * 9, ctx_hyp_trans + bb * 3, Rp, tp);
            rel_tf(gt_rot + bb * 9, gt_trans + bb * 3,
                   ctx_gt_rot + bb * 9, ctx_gt_trans + bb * 3, Rg, tg);
            lt += fabsf(tp[0] - tg[0]) + fabsf(tp[1] - tg[1]) + fabsf(tp[2] - tg[2]);
        }
        out[1] = lt / (float)(3 * B);
    }
}

// grid.x = 2 * B * (N / (TPB/64 * RW)); each wave: RW rows, lanes split m.
__global__ void __launch_bounds__(TPB, 8) k_chamfer(
        const float4* __restrict__ pts, float* __restrict__ out,
        int B, int N) {
    const int wave = threadIdx.x >> 6;
    const int lane = threadIdx.x & 63;
    const int rowsPerBlock = (TPB / 64) * RW;           // 32
    const int blocksPerB = N / rowsPerBlock;            // 128
    int bid = blockIdx.x;
    int dir = bid / (B * blocksPerB);
    int rem = bid % (B * blocksPerB);
    int b = rem / blocksPerB;
    int rblk = rem % blocksPerB;

    const float4* Ap = pts + ((size_t)dir * B + b) * N;
    const float4* Bp = pts + ((size_t)(1 - dir) * B + b) * N;
    int rowBase = rblk * rowsPerBlock + wave * RW;

    float a2x[RW], a2y[RW], a2z[RW], mn[RW];
#pragma unroll
    for (int r = 0; r < RW; r++) {
        float4 a = Ap[rowBase + r];     // same addr all lanes -> broadcast
        a2x[r] = -2.0f * a.x;
        a2y[r] = -2.0f * a.y;
        a2z[r] = -2.0f * a.z;
        mn[r] = INFINITY;
    }

    // main loop: lane L covers m = L, L+64, ... Coalesced dwordx4 loads.
#pragma unroll 2
    for (int mm = 0; mm < N; mm += 64) {
        float4 g = Bp[mm + lane];
#pragma unroll
        for (int r = 0; r < RW; r++) {
            float p = __builtin_fmaf(a2x[r], g.x, g.w);
            p = __builtin_fmaf(a2y[r], g.y, p);
            p = __builtin_fmaf(a2z[r], g.z, p);
            mn[r] = fminf(mn[r], p);
        }
    }

    // finish rows in-wave: butterfly min, add ||a||^2, sqrt, accumulate.
    float s = 0.0f;
#pragma unroll
    for (int r = 0; r < RW; r++) {
        float m = mn[r];
#pragma unroll
        for (int off = 32; off > 0; off >>= 1)
            m = fminf(m, __shfl_xor(m, off, 64));
        float aw = Ap[rowBase + r].w;   // broadcast re-load (saves 8 VGPRs)
        s += sqrtf(fmaxf(m + aw, 0.0f));
    }

    __shared__ float red[TPB / 64];
    if (lane == 0) red[wave] = s;
    __syncthreads();
    if (threadIdx.x == 0) {
        float t = 0.0f;
#pragma unroll
        for (int w = 0; w < TPB / 64; w++) t += red[w];
        atomicAdd(&out[0], t / (float)(B * N));
    }
}

extern "C" void kernel_launch(void* const* d_in, const int* in_sizes, int n_in,
                              void* d_out, int out_size, void* d_ws, size_t ws_size,
                              hipStream_t stream) {
    const float* pred_rot      = (const float*)d_in[0];
    const float* pred_trans    = (const float*)d_in[1];
    const float* ctx_hyp_rot   = (const float*)d_in[2];
    const float* ctx_hyp_trans = (const float*)d_in[3];
    const float* gt_rot        = (const float*)d_in[4];
    const float* gt_trans      = (const float*)d_in[5];
    const float* ctx_gt_rot    = (const float*)d_in[6];
    const float* ctx_gt_trans  = (const float*)d_in[7];
    const float* model_points  = (const float*)d_in[8];

    int B = in_sizes[0] / 9;
    int N = in_sizes[8] / (3 * B);

    float4* pts = (float4*)d_ws;
    float*  out = (float*)d_out;

    k_prep<<<(B * N + TPB - 1) / TPB, TPB, 0, stream>>>(
        pred_rot, pred_trans, ctx_hyp_rot, ctx_hyp_trans,
        gt_rot, gt_trans, ctx_gt_rot, ctx_gt_trans,
        model_points, pts, out, B, N);

    int rowsPerBlock = (TPB / 64) * RW;                    // 32
    int grid = 2 * B * (N / rowsPerBlock);                 // 2048
    k_chamfer<<<grid, TPB, 0, stream>>>(pts, out, B, N);
}

// Round 6
// 105.935 us; speedup vs baseline: 1.1199x; 1.1199x over previous
//
#include <hip/hip_runtime.h>
#include <hip/hip_bf16.h>
#include <math.h>

// RelativeGeoSymLoss: B=8, N=4096 symmetric chamfer + trans L1.
// R6: block stages the ENTIRE opposing point set in LDS as packed fp16
// pairs (32 KB, one barrier). Each wave owns RW=16 rows; lanes split m,
// reading stride-1 ds_read_b128 (2 points / 16 B / lane-iter). Inner math
// is packed fp16: 2 instructions per (row, point) pair. Rows finish
// in-wave (butterfly min), fp32 epilogue, one atomicAdd per block.
// ws layout: pts [2][B][N] float4 (x,y,z,||.||^2) only.

#define TPB 256
#define RW  16   // rows per wave; block rows = 4 waves * 16 = 64

typedef _Float16 h2 __attribute__((ext_vector_type(2)));
struct alignas(16) G8 { h2 x, y, z, w; };  // two packed m-points

__device__ __forceinline__ void rel_tf(const float* __restrict__ Ra,
                                       const float* __restrict__ ta,
                                       const float* __restrict__ Rb,
                                       const float* __restrict__ tb,
                                       float* R, float* t) {
#pragma unroll
    for (int i = 0; i < 3; i++)
#pragma unroll
        for (int k = 0; k < 3; k++)
            R[i * 3 + k] = Ra[i * 3 + 0] * Rb[k * 3 + 0]
                         + Ra[i * 3 + 1] * Rb[k * 3 + 1]
                         + Ra[i * 3 + 2] * Rb[k * 3 + 2];
#pragma unroll
    for (int i = 0; i < 3; i++)
        t[i] = ta[i] - (R[i * 3 + 0] * tb[0] + R[i * 3 + 1] * tb[1]
                      + R[i * 3 + 2] * tb[2]);
}

// Fused: relative transforms + point transform + out init.
__global__ void k_prep(const float* __restrict__ pred_rot,
                       const float* __restrict__ pred_trans,
                       const float* __restrict__ ctx_hyp_rot,
                       const float* __restrict__ ctx_hyp_trans,
                       const float* __restrict__ gt_rot,
                       const float* __restrict__ gt_trans,
                       const float* __restrict__ ctx_gt_rot,
                       const float* __restrict__ ctx_gt_trans,
                       const float* __restrict__ mp,
                       float4* __restrict__ pts,
                       float* __restrict__ out, int B, int N) {
    int idx = blockIdx.x * blockDim.x + threadIdx.x;
    if (idx >= B * N) return;
    int b = idx / N;
    float px = mp[idx * 3 + 0], py = mp[idx * 3 + 1], pz = mp[idx * 3 + 2];
    float R[9], t[3];
#pragma unroll
    for (int g = 0; g < 2; g++) {
        if (g == 0)
            rel_tf(pred_rot + b * 9, pred_trans + b * 3,
                   ctx_hyp_rot + b * 9, ctx_hyp_trans + b * 3, R, t);
        else
            rel_tf(gt_rot + b * 9, gt_trans + b * 3,
                   ctx_gt_rot + b * 9, ctx_gt_trans + b * 3, R, t);
        float x = R[0] * px + R[1] * py + R[2] * pz + t[0];
        float y = R[3] * px + R[4] * py + R[5] * pz + t[1];
        float z = R[6] * px + R[7] * py + R[8] * pz + t[2];
        pts[(size_t)g * B * N + idx] = make_float4(x, y, z, x * x + y * y + z * z);
    }
    if (idx == 0) {
        out[0] = 0.0f;
        float lt = 0.0f;
        for (int bb = 0; bb < B; bb++) {
            float Rp[9], tp[3], Rg[9], tg[3];
            rel_tf(pred_rot + bb * 9, pred_trans + bb * 3,
                   ctx_hyp_rot + bb * 9, ctx_hyp_trans + bb * 3, Rp, tp);
            rel_tf(gt_rot + bb * 9, gt_trans + bb * 3,
                   ctx_gt_rot + bb * 9, ctx_gt_trans + bb * 3, Rg, tg);
            lt += fabsf(tp[0] - tg[0]) + fabsf(tp[1] - tg[1]) + fabsf(tp[2] - tg[2]);
        }
        out[1] = lt / (float)(3 * B);
    }
}

// grid = 2 * B * (N/64) = 1024 blocks; LDS 32 KB -> 4 blocks/CU.
__global__ void __launch_bounds__(TPB, 4) k_chamfer(
        const float4* __restrict__ pts, float* __restrict__ out,
        int B, int N) {
    const int wave = threadIdx.x >> 6;
    const int lane = threadIdx.x & 63;
    const int rowsPerBlock = (TPB / 64) * RW;           // 64
    const int blocksPerB = N / rowsPerBlock;            // 64
    int bid = blockIdx.x;
    int dir = bid / (B * blocksPerB);
    int rem = bid % (B * blocksPerB);
    int b = rem / blocksPerB;
    int rblk = rem % blocksPerB;

    const float4* Ap = pts + ((size_t)dir * B + b) * N;
    const float4* Bp = pts + ((size_t)(1 - dir) * B + b) * N;
    int rowBase = rblk * rowsPerBlock + wave * RW;

    // Stage the full opposing set, packed 2-points-per-G8 (32 KB).
    __shared__ G8 sB[2048];
    for (int i = threadIdx.x; i < N / 2; i += TPB) {
        float4 g0 = Bp[2 * i];
        float4 g1 = Bp[2 * i + 1];
        G8 e;
        e.x.x = (_Float16)g0.x; e.x.y = (_Float16)g1.x;
        e.y.x = (_Float16)g0.y; e.y.y = (_Float16)g1.y;
        e.z.x = (_Float16)g0.z; e.z.y = (_Float16)g1.z;
        e.w.x = (_Float16)g0.w; e.w.y = (_Float16)g1.w;
        sB[i] = e;
    }

    // Row registers: -2*coords splatted to fp16 pairs.
    h2 a2x[RW], a2y[RW], a2z[RW], mn[RW];
#pragma unroll
    for (int r = 0; r < RW; r++) {
        float4 a = Ap[rowBase + r];     // uniform -> broadcast
        _Float16 vx = (_Float16)(-2.0f * a.x);
        _Float16 vy = (_Float16)(-2.0f * a.y);
        _Float16 vz = (_Float16)(-2.0f * a.z);
        a2x[r].x = vx; a2x[r].y = vx;
        a2y[r].x = vy; a2y[r].y = vy;
        a2z[r].x = vz; a2z[r].y = vz;
        mn[r].x = (_Float16)65504.0f; mn[r].y = (_Float16)65504.0f;
    }
    __syncthreads();

    // Main loop: lane L covers G8 entries L, L+64, ... (stride-1 b128).
#pragma unroll 2
    for (int j = lane; j < N / 2; j += 64) {
        G8 g = sB[j];
#pragma unroll
        for (int r = 0; r < RW; r++) {
            h2 p = __builtin_elementwise_fma(a2z[r], g.z, g.w);
            p = __builtin_elementwise_fma(a2y[r], g.y, p);
            p = __builtin_elementwise_fma(a2x[r], g.x, p);
            mn[r] = __builtin_elementwise_min(mn[r], p);
        }
    }

    // Finish rows in-wave: fp32 butterfly min, + ||a||^2, sqrt, accumulate.
    float s = 0.0f;
#pragma unroll
    for (int r = 0; r < RW; r++) {
        float m = fminf((float)mn[r].x, (float)mn[r].y);
#pragma unroll
        for (int off = 32; off > 0; off >>= 1)
            m = fminf(m, __shfl_xor(m, off, 64));
        float aw = Ap[rowBase + r].w;   // uniform re-load
        s += sqrtf(fmaxf(m + aw, 0.0f));
    }

    __shared__ float red[TPB / 64];
    if (lane == 0) red[wave] = s;
    __syncthreads();
    if (threadIdx.x == 0) {
        float t = 0.0f;
#pragma unroll
        for (int w = 0; w < TPB / 64; w++) t += red[w];
        atomicAdd(&out[0], t / (float)(B * N));
    }
}

extern "C" void kernel_launch(void* const* d_in, const int* in_sizes, int n_in,
                              void* d_out, int out_size, void* d_ws, size_t ws_size,
                              hipStream_t stream) {
    const float* pred_rot      = (const float*)d_in[0];
    const float* pred_trans    = (const float*)d_in[1];
    const float* ctx_hyp_rot   = (const float*)d_in[2];
    const float* ctx_hyp_trans = (const float*)d_in[3];
    const float* gt_rot        = (const float*)d_in[4];
    const float* gt_trans      = (const float*)d_in[5];
    const float* ctx_gt_rot    = (const float*)d_in[6];
    const float* ctx_gt_trans  = (const float*)d_in[7];
    const float* model_points  = (const float*)d_in[8];

    int B = in_sizes[0] / 9;
    int N = in_sizes[8] / (3 * B);

    float4* pts = (float4*)d_ws;
    float*  out = (float*)d_out;

    k_prep<<<(B * N + TPB - 1) / TPB, TPB, 0, stream>>>(
        pred_rot, pred_trans, ctx_hyp_rot, ctx_hyp_trans,
        gt_rot, gt_trans, ctx_gt_rot, ctx_gt_trans,
        model_points, pts, out, B, N);

    int rowsPerBlock = (TPB / 64) * RW;                    // 64
    int grid = 2 * B * (N / rowsPerBlock);                 // 1024
    k_chamfer<<<grid, TPB, 0, stream>>>(pts, out, B, N);
}

// Round 7
// 103.539 us; speedup vs baseline: 1.1458x; 1.0231x over previous
//
#include <hip/hip_runtime.h>
#include <hip/hip_bf16.h>
#include <math.h>

// RelativeGeoSymLoss: B=8, N=4096 symmetric chamfer + trans L1.
// R7: ONE self-contained kernel. Both clouds derive from model_points[b],
// so each block: (1) loads raw points (48 KB, L2-resident), transforms with
// the OPPOSING (R,t), packs fp16 pairs into 32 KB LDS; (2) waves transform
// their own RW=16 A-rows with their OWN (R,t) from uniform loads;
// (3) lanes split m over LDS (stride-1 ds_read_b128), packed fp16 inner
// loop (2 inst/pair); (4) in-wave butterfly min, fp32 sqrt+sum, one
// atomicAdd per block. No workspace at all; out[0] zeroed via memset.

#define TPB 256
#define RW  16   // rows per wave; block rows = 4 * 16 = 64

typedef _Float16 h2 __attribute__((ext_vector_type(2)));
struct alignas(16) G8 { h2 x, y, z, w; };  // two packed m-points

__device__ __forceinline__ void rel_tf(const float* __restrict__ Ra,
                                       const float* __restrict__ ta,
                                       const float* __restrict__ Rb,
                                       const float* __restrict__ tb,
                                       float* R, float* t) {
#pragma unroll
    for (int i = 0; i < 3; i++)
#pragma unroll
        for (int k = 0; k < 3; k++)
            R[i * 3 + k] = Ra[i * 3 + 0] * Rb[k * 3 + 0]
                         + Ra[i * 3 + 1] * Rb[k * 3 + 1]
                         + Ra[i * 3 + 2] * Rb[k * 3 + 2];
#pragma unroll
    for (int i = 0; i < 3; i++)
        t[i] = ta[i] - (R[i * 3 + 0] * tb[0] + R[i * 3 + 1] * tb[1]
                      + R[i * 3 + 2] * tb[2]);
}

// grid = 2 * B * (N/64) = 1024 blocks; LDS 32 KB -> 4 blocks/CU.
__global__ void __launch_bounds__(TPB, 4) k_fused(
        const float* __restrict__ pred_rot,
        const float* __restrict__ pred_trans,
        const float* __restrict__ ctx_hyp_rot,
        const float* __restrict__ ctx_hyp_trans,
        const float* __restrict__ gt_rot,
        const float* __restrict__ gt_trans,
        const float* __restrict__ ctx_gt_rot,
        const float* __restrict__ ctx_gt_trans,
        const float* __restrict__ mp,
        float* __restrict__ out, int B, int N) {
    const int wave = threadIdx.x >> 6;
    const int lane = threadIdx.x & 63;
    const int rowsPerBlock = (TPB / 64) * RW;           // 64
    const int blocksPerB = N / rowsPerBlock;            // 64
    int bid = blockIdx.x;
    int dir = bid / (B * blocksPerB);
    int rem = bid % (B * blocksPerB);
    int b = rem / blocksPerB;
    int rblk = rem % blocksPerB;

    // Own and opposing transforms (tiny, cached reads; recomputed per thread).
    float Ra[9], ta[3], Ro[9], to[3];
    if (dir == 0) {
        rel_tf(pred_rot + b * 9, pred_trans + b * 3,
               ctx_hyp_rot + b * 9, ctx_hyp_trans + b * 3, Ra, ta);
        rel_tf(gt_rot + b * 9, gt_trans + b * 3,
               ctx_gt_rot + b * 9, ctx_gt_trans + b * 3, Ro, to);
    } else {
        rel_tf(gt_rot + b * 9, gt_trans + b * 3,
               ctx_gt_rot + b * 9, ctx_gt_trans + b * 3, Ra, ta);
        rel_tf(pred_rot + b * 9, pred_trans + b * 3,
               ctx_hyp_rot + b * 9, ctx_hyp_trans + b * 3, Ro, to);
    }

    const float* P = mp + (size_t)b * N * 3;

    // Stage opposing cloud: 16 points/thread, transform, pack fp16 (32 KB).
    __shared__ G8 sB[2048];
    {
        float buf[48];
        const float4* P4 = (const float4*)(P + threadIdx.x * 48);
#pragma unroll
        for (int q = 0; q < 12; q++) ((float4*)buf)[q] = P4[q];
#pragma unroll
        for (int k = 0; k < 8; k++) {
            float x0, y0, z0, w0, x1, y1, z1, w1;
#pragma unroll
            for (int h = 0; h < 2; h++) {
                const float* p = buf + (2 * k + h) * 3;
                float x = Ro[0] * p[0] + Ro[1] * p[1] + Ro[2] * p[2] + to[0];
                float y = Ro[3] * p[0] + Ro[4] * p[1] + Ro[5] * p[2] + to[1];
                float z = Ro[6] * p[0] + Ro[7] * p[1] + Ro[8] * p[2] + to[2];
                float w = x * x + y * y + z * z;
                if (h == 0) { x0 = x; y0 = y; z0 = z; w0 = w; }
                else        { x1 = x; y1 = y; z1 = z; w1 = w; }
            }
            G8 e;
            e.x.x = (_Float16)x0; e.x.y = (_Float16)x1;
            e.y.x = (_Float16)y0; e.y.y = (_Float16)y1;
            e.z.x = (_Float16)z0; e.z.y = (_Float16)z1;
            e.w.x = (_Float16)w0; e.w.y = (_Float16)w1;
            sB[threadIdx.x * 8 + k] = e;
        }
    }

    // Own A-rows: uniform loads + own transform; -2x coords as fp16 pairs.
    int rowBase = rblk * rowsPerBlock + wave * RW;
    h2 a2x[RW], a2y[RW], a2z[RW], mn[RW];
    float aw[RW];
#pragma unroll
    for (int r = 0; r < RW; r++) {
        const float* p = P + (rowBase + r) * 3;
        float px = p[0], py = p[1], pz = p[2];   // uniform -> s-load/broadcast
        float x = Ra[0] * px + Ra[1] * py + Ra[2] * pz + ta[0];
        float y = Ra[3] * px + Ra[4] * py + Ra[5] * pz + ta[1];
        float z = Ra[6] * px + Ra[7] * py + Ra[8] * pz + ta[2];
        aw[r] = x * x + y * y + z * z;
        _Float16 vx = (_Float16)(-2.0f * x);
        _Float16 vy = (_Float16)(-2.0f * y);
        _Float16 vz = (_Float16)(-2.0f * z);
        a2x[r].x = vx; a2x[r].y = vx;
        a2y[r].x = vy; a2y[r].y = vy;
        a2z[r].x = vz; a2z[r].y = vz;
        mn[r].x = (_Float16)65504.0f; mn[r].y = (_Float16)65504.0f;
    }
    __syncthreads();

    // Main loop: lane L covers G8 entries L, L+64, ... (stride-1 b128).
#pragma unroll 2
    for (int j = lane; j < N / 2; j += 64) {
        G8 g = sB[j];
#pragma unroll
        for (int r = 0; r < RW; r++) {
            h2 p = __builtin_elementwise_fma(a2z[r], g.z, g.w);
            p = __builtin_elementwise_fma(a2y[r], g.y, p);
            p = __builtin_elementwise_fma(a2x[r], g.x, p);
            mn[r] = __builtin_elementwise_min(mn[r], p);
        }
    }

    // Finish rows in-wave: fp32 butterfly min, + ||a||^2, sqrt, accumulate.
    float s = 0.0f;
#pragma unroll
    for (int r = 0; r < RW; r++) {
        float m = fminf((float)mn[r].x, (float)mn[r].y);
#pragma unroll
        for (int off = 32; off > 0; off >>= 1)
            m = fminf(m, __shfl_xor(m, off, 64));
        s += sqrtf(fmaxf(m + aw[r], 0.0f));
    }

    __shared__ float red[TPB / 64];
    if (lane == 0) red[wave] = s;
    __syncthreads();
    if (threadIdx.x == 0) {
        float t = 0.0f;
#pragma unroll
        for (int w = 0; w < TPB / 64; w++) t += red[w];
        atomicAdd(&out[0], t / (float)(B * N));
    }

    // Trans L1 loss once globally.
    if (bid == 0 && threadIdx.x == 0) {
        float lt = 0.0f;
        for (int bb = 0; bb < B; bb++) {
            float Rp[9], tp[3], Rg[9], tg[3];
            rel_tf(pred_rot + bb * 9, pred_trans + bb * 3,
                   ctx_hyp_rot + bb * 9, ctx_hyp_trans + bb * 3, Rp, tp);
            rel_tf(gt_rot + bb * 9, gt_trans + bb * 3,
                   ctx_gt_rot + bb * 9, ctx_gt_trans + bb * 3, Rg, tg);
            lt += fabsf(tp[0] - tg[0]) + fabsf(tp[1] - tg[1]) + fabsf(tp[2] - tg[2]);
        }
        out[1] = lt / (float)(3 * B);
    }
}

extern "C" void kernel_launch(void* const* d_in, const int* in_sizes, int n_in,
                              void* d_out, int out_size, void* d_ws, size_t ws_size,
                              hipStream_t stream) {
    const float* pred_rot      = (const float*)d_in[0];
    const float* pred_trans    = (const float*)d_in[1];
    const float* ctx_hyp_rot   = (const float*)d_in[2];
    const float* ctx_hyp_trans = (const float*)d_in[3];
    const float* gt_rot        = (const float*)d_in[4];
    const float* gt_trans      = (const float*)d_in[5];
    const float* ctx_gt_rot    = (const float*)d_in[6];
    const float* ctx_gt_trans  = (const float*)d_in[7];
    const float* model_points  = (const float*)d_in[8];

    int B = in_sizes[0] / 9;
    int N = in_sizes[8] / (3 * B);

    float* out = (float*)d_out;
    hipMemsetAsync(out, 0, 2 * sizeof(float), stream);

    int rowsPerBlock = (TPB / 64) * RW;                    // 64
    int grid = 2 * B * (N / rowsPerBlock);                 // 1024
    k_fused<<<grid, TPB, 0, stream>>>(
        pred_rot, pred_trans, ctx_hyp_rot, ctx_hyp_trans,
        gt_rot, gt_trans, ctx_gt_rot, ctx_gt_trans,
        model_points, out, B, N);
}